// Round 13
// baseline (133.611 us; speedup 1.0000x reference)
//
#include <hip/hip_runtime.h>

typedef __attribute__((ext_vector_type(4))) float f32x4;
typedef __attribute__((ext_vector_type(16))) float f32x16;
typedef __attribute__((ext_vector_type(8))) __bf16 bf16x8;
typedef __attribute__((ext_vector_type(4))) unsigned short u16x4;
typedef __attribute__((ext_vector_type(2))) unsigned int u32x2;

#define DEVI static __device__ __forceinline__

DEVI unsigned short bf16_bits(float f) {
  __bf16 h = (__bf16)f;
  return __builtin_bit_cast(unsigned short, h);
}

DEVI float bf16_f32(__bf16 u) { return (float)u; }

DEVI void gl_lds16(const void* g, void* l) {
  __builtin_amdgcn_global_load_lds(
      (const __attribute__((address_space(1))) void*)g,
      (__attribute__((address_space(3))) void*)l, 16, 0, 0);
}

DEVI f32x4 mfma16x16(bf16x8 a, bf16x8 b, f32x4 c) {
  return __builtin_amdgcn_mfma_f32_16x16x32_bf16(a, b, c, 0, 0, 0);
}

DEVI f32x16 mfma32(bf16x8 a, bf16x8 b, f32x16 c) {
  return __builtin_amdgcn_mfma_f32_32x32x16_bf16(a, b, c, 0, 0, 0);
}

DEVI unsigned cvtpk_bf16(float lo, float hi2) {
  unsigned r;
  asm("v_cvt_pk_bf16_f32 %0, %1, %2" : "=v"(r) : "v"(lo), "v"(hi2));
  return r;
}

// NOTE (r3/r4 lesson): never call with two copies of the same value — the
// allocator may coalesce them into ONE register and the swap degenerates.
DEVI void pl32swap(unsigned& a, unsigned& b) {
  asm volatile("s_nop 1\nv_permlane32_swap_b32 %0, %1\ns_nop 1"
               : "+v"(a), "+v"(b));
}

#define WAITVM0 asm volatile("s_waitcnt vmcnt(0)" ::: "memory")

// ---------------------------------------------------------------- prep
// Round-13: fused ln (blocks 0..4095) + w_qkv transpose (4096..4863) +
// w_out transpose (4864..5119). Block-uniform branch; bodies verified r1-r12.
__global__ __launch_bounds__(256) void prep_kernel(
    const float* __restrict__ x, const float* __restrict__ gamma,
    const float* __restrict__ beta, __bf16* __restrict__ xn,
    const float* __restrict__ w_qkv, __bf16* __restrict__ wqkvT,
    const float* __restrict__ w_out, __bf16* __restrict__ woutT) {
  __shared__ float tile[64][65];
  __shared__ float red[8];
  int blk = blockIdx.x;
  int t = threadIdx.x;
  if (blk < 4096) {
    int row = blk;
    float4 v = ((const float4*)(x + (size_t)row * 1024))[t];
    float s = v.x + v.y + v.z + v.w;
    float sq = v.x * v.x + v.y * v.y + v.z * v.z + v.w * v.w;
#pragma unroll
    for (int off = 32; off > 0; off >>= 1) {
      s += __shfl_down(s, off);
      sq += __shfl_down(sq, off);
    }
    int w = t >> 6, ln = t & 63;
    if (ln == 0) { red[w] = s; red[4 + w] = sq; }
    __syncthreads();
    s = red[0] + red[1] + red[2] + red[3];
    sq = red[4] + red[5] + red[6] + red[7];
    float mu = s * (1.0f / 1024.0f);
    float var = sq * (1.0f / 1024.0f) - mu * mu;
    float rstd = rsqrtf(var + 1e-5f);
    float4 g = ((const float4*)gamma)[t];
    float4 b = ((const float4*)beta)[t];
    u16x4 o;
    o[0] = bf16_bits((v.x - mu) * rstd * g.x + b.x);
    o[1] = bf16_bits((v.y - mu) * rstd * g.y + b.y);
    o[2] = bf16_bits((v.z - mu) * rstd * g.z + b.z);
    o[3] = bf16_bits((v.w - mu) * rstd * g.w + b.w);
    *(u16x4*)(xn + (size_t)row * 1024 + t * 4) = o;
    return;
  }
  // transpose fp32 [R][C] -> bf16 [C][R]
  const float* in;
  __bf16* out;
  int R, C, bx, by;
  if (blk < 4096 + 768) {
    int i2 = blk - 4096;
    in = w_qkv; out = wqkvT; R = 1024; C = 3072;
    bx = i2 % 48; by = i2 / 48;
  } else {
    int i3 = blk - 4864;
    in = w_out; out = woutT; R = 1024; C = 1024;
    bx = i3 % 16; by = i3 / 16;
  }
  int tx = t & 15, ty = t >> 4;
  int c0 = bx * 64, r0 = by * 64;
#pragma unroll
  for (int p = 0; p < 4; ++p) {
    int r = ty + p * 16;
    float4 v = *(const float4*)(in + (size_t)(r0 + r) * C + c0 + tx * 4);
    tile[r][tx * 4 + 0] = v.x;
    tile[r][tx * 4 + 1] = v.y;
    tile[r][tx * 4 + 2] = v.z;
    tile[r][tx * 4 + 3] = v.w;
  }
  __syncthreads();
#pragma unroll
  for (int p = 0; p < 4; ++p) {
    int cc = ty + p * 16;
    u16x4 o;
    o[0] = bf16_bits(tile[tx * 4 + 0][cc]);
    o[1] = bf16_bits(tile[tx * 4 + 1][cc]);
    o[2] = bf16_bits(tile[tx * 4 + 2][cc]);
    o[3] = bf16_bits(tile[tx * 4 + 3][cc]);
    *(u16x4*)(out + (size_t)(c0 + cc) * R + r0 + tx * 4) = o;
  }
}

// ---------------------------------------------------------------- QKV GEMM
// Round-13: Q/K n-blocks (n0<2048) use SWAPPED mfma(bfr, af) -> acc holds
// C^T fragment: row=(ln>>4)*4+reg = n(feature), col=lrow = m(seq). Per lane
// the 4 acc values are 4 consecutive d at fixed seq -> one u16x4 store
// (was 4 scalar 2B stores). V third keeps normal orientation (seq-contiguous
// u16x4 store, verified). Values bitwise identical either way.
__global__ __launch_bounds__(256) void gemm_qkv_kernel(
    const __bf16* __restrict__ A, const __bf16* __restrict__ BT,
    __bf16* __restrict__ Qb, __bf16* __restrict__ Kb, __bf16* __restrict__ VTb) {
  __shared__ __align__(16) __bf16 Asm[128 * 32];
  __shared__ __align__(16) __bf16 Bsm[128 * 32];
  const int KD = 1024;
  int t = threadIdx.x;
  int w = t >> 6, ln = t & 63;
  int wr = w >> 1, wc = w & 1;
  int m0 = blockIdx.y * 128, n0 = blockIdx.x * 128;
  bool swapQK = (n0 < 2048);  // block-uniform (tiles 0-15 Q/K, 16-23 V)
  f32x4 acc[4][4] = {};

  int srow = w * 16 + (ln >> 2);
  int scol = (ln & 3) * 8;
  int lrow = ln & 15;
  int lkb = (ln >> 4) * 16;

  for (int kk = 0; kk < KD; kk += 32) {
    __syncthreads();
#pragma unroll
    for (int i = 0; i < 2; ++i) {
      int row = i * 64 + srow;
      gl_lds16(A + (size_t)(m0 + row) * KD + kk + scol,
               (char*)Asm + i * 4096 + w * 1024);
      gl_lds16(BT + (size_t)(n0 + row) * KD + kk + scol,
               (char*)Bsm + i * 4096 + w * 1024);
    }
    __syncthreads();
    bf16x8 af[4], bfr[4];
#pragma unroll
    for (int mi = 0; mi < 4; ++mi)
      af[mi] = *(const bf16x8*)((char*)Asm + (wr * 64 + mi * 16 + lrow) * 64 + lkb);
#pragma unroll
    for (int ni = 0; ni < 4; ++ni)
      bfr[ni] = *(const bf16x8*)((char*)Bsm + (wc * 64 + ni * 16 + lrow) * 64 + lkb);
    if (swapQK) {
#pragma unroll
      for (int mi = 0; mi < 4; ++mi)
#pragma unroll
        for (int ni = 0; ni < 4; ++ni)
          acc[mi][ni] = mfma16x16(bfr[ni], af[mi], acc[mi][ni]);
    } else {
#pragma unroll
      for (int mi = 0; mi < 4; ++mi)
#pragma unroll
        for (int ni = 0; ni < 4; ++ni)
          acc[mi][ni] = mfma16x16(af[mi], bfr[ni], acc[mi][ni]);
    }
  }

  int r4 = (ln >> 4) * 4;
  if (swapQK) {
    // acc = C^T: col=lrow=seq-within-16, row=r4+r=feature-within-16
#pragma unroll
    for (int mi = 0; mi < 4; ++mi) {
#pragma unroll
      for (int ni = 0; ni < 4; ++ni) {
        int seq_g = m0 + wr * 64 + mi * 16 + lrow;
        int nfeat = n0 + wc * 64 + ni * 16 + r4;  // 4 consecutive n
        int sel = nfeat >> 10;                    // 0=Q 1=K
        int nl = nfeat & 1023;
        int h = nl >> 6, d0 = nl & 63;
        int b = seq_g >> 11, seq = seq_g & 2047;
        int bh = b * 16 + h;
        __bf16* dst = (sel == 0 ? Qb : Kb);
        u16x4 o;
        o[0] = bf16_bits(acc[mi][ni][0]);
        o[1] = bf16_bits(acc[mi][ni][1]);
        o[2] = bf16_bits(acc[mi][ni][2]);
        o[3] = bf16_bits(acc[mi][ni][3]);
        *(u16x4*)(dst + ((size_t)bh * 2048 + seq) * 64 + d0) = o;
      }
    }
  } else {
    // normal: col=lrow=n, rows=r4+r=m(seq) -> VT store seq-contiguous
#pragma unroll
    for (int mi = 0; mi < 4; ++mi) {
#pragma unroll
      for (int ni = 0; ni < 4; ++ni) {
        int grow = m0 + wr * 64 + mi * 16 + r4;
        int gcol = n0 + wc * 64 + ni * 16 + lrow;
        int nl = gcol & 1023;
        int h = nl >> 6, d = nl & 63;
        int b = grow >> 11, seq = grow & 2047;
        int bh = b * 16 + h;
        u16x4 o;
        o[0] = bf16_bits(acc[mi][ni][0]);
        o[1] = bf16_bits(acc[mi][ni][1]);
        o[2] = bf16_bits(acc[mi][ni][2]);
        o[3] = bf16_bits(acc[mi][ni][3]);
        *(u16x4*)(VTb + ((size_t)bh * 64 + d) * 2048 + seq) = o;
      }
    }
  }
}

// ---------------------------------------------------------------- out GEMM
// Round-13: SWAPPED orientation everywhere -> per-lane 4 consecutive n at
// fixed m -> float4 C store + float4 bias load (was 4 scalar dword stores).
__global__ __launch_bounds__(256) void gemm_out_kernel(
    const __bf16* __restrict__ A, const __bf16* __restrict__ BT,
    float* __restrict__ Cout, const float* __restrict__ bias) {
  __shared__ __align__(16) __bf16 Asm[128 * 32];  // 8KB
  __shared__ __align__(16) __bf16 Bsm[64 * 32];   // 4KB
  const int KD = 1024;
  int t = threadIdx.x;
  int w = t >> 6, ln = t & 63;
  int m0 = blockIdx.y * 128, n0 = blockIdx.x * 64;
  f32x4 acc[2][4] = {};

  int srow = w * 16 + (ln >> 2);  // 0..63
  int scol = (ln & 3) * 8;
  int lrow = ln & 15;
  int lkb = (ln >> 4) * 16;

  for (int kk = 0; kk < KD; kk += 32) {
    __syncthreads();
#pragma unroll
    for (int i = 0; i < 2; ++i)
      gl_lds16(A + (size_t)(m0 + i * 64 + srow) * KD + kk + scol,
               (char*)Asm + i * 4096 + w * 1024);
    gl_lds16(BT + (size_t)(n0 + srow) * KD + kk + scol, (char*)Bsm + w * 1024);
    __syncthreads();
    bf16x8 af[2], bfr[4];
#pragma unroll
    for (int mi = 0; mi < 2; ++mi)
      af[mi] = *(const bf16x8*)((char*)Asm + (w * 32 + mi * 16 + lrow) * 64 + lkb);
#pragma unroll
    for (int ni = 0; ni < 4; ++ni)
      bfr[ni] = *(const bf16x8*)((char*)Bsm + (ni * 16 + lrow) * 64 + lkb);
#pragma unroll
    for (int mi = 0; mi < 2; ++mi)
#pragma unroll
      for (int ni = 0; ni < 4; ++ni)
        acc[mi][ni] = mfma16x16(bfr[ni], af[mi], acc[mi][ni]);  // swapped
  }

  int r4 = (ln >> 4) * 4;
#pragma unroll
  for (int mi = 0; mi < 2; ++mi) {
#pragma unroll
    for (int ni = 0; ni < 4; ++ni) {
      int m = m0 + w * 32 + mi * 16 + lrow;
      int nb = n0 + ni * 16 + r4;  // 4 consecutive n
      float4 bv = *(const float4*)(bias + nb);
      float4 o;
      o.x = acc[mi][ni][0] + bv.x;
      o.y = acc[mi][ni][1] + bv.y;
      o.z = acc[mi][ni][2] + bv.z;
      o.w = acc[mi][ni][3] + bv.w;
      *(float4*)(Cout + (size_t)m * 1024 + nb) = o;
    }
  }
}

// ---------------------------------------------------------------- attention
// r11-verified: j-SPLIT flash (exact under no-max softmax), grid (16,32,2).
__global__ __launch_bounds__(256, 2) void attn_kernel(
    const __bf16* __restrict__ Qb, const __bf16* __restrict__ Kb,
    const __bf16* __restrict__ VTb, __bf16* __restrict__ Opart,
    float* __restrict__ lbuf) {
  __shared__ __align__(16) char Klds[16384];   // 2 bufs x [64 j][128B], swizzled
  __shared__ __align__(16) char Vlds[16384];   // 2 bufs x [64 d][128B], swizzled
  const float LOG2E = 1.44269504f;
  const float K1 = 0.125f * LOG2E;
  int t = threadIdx.x, w = t >> 6, ln = t & 63;
  int hi = ln >> 5, col = ln & 31;
  int bh = blockIdx.y, bq = bh >> 4, h = bh & 15;
  int q0 = blockIdx.x * 128;
  int jh = blockIdx.z;                 // j-half: tiles jh*16 .. jh*16+15
  const __bf16* Qh = Qb + (size_t)bh * 2048 * 64;
  const __bf16* Kh = Kb + (size_t)bh * 2048 * 64;
  const __bf16* Vh = VTb + (size_t)bh * 64 * 2048;
  __bf16* Oh = Opart + (size_t)jh * 4096 * 1024;  // half = 4M bf16 = 8MB

  bf16x8 qf[4];
  int qrow = q0 + w * 32 + col;
#pragma unroll
  for (int dk = 0; dk < 4; ++dk)
    qf[dk] = *(const bf16x8*)(Qh + (size_t)qrow * 64 + dk * 16 + hi * 8);

  f32x16 oacc0 = {}, oacc1 = {};
  float l_run = 0.f;

  int sj0 = t >> 3, sc0 = (t & 7) ^ (sj0 & 7);
  int sj1 = 32 + (t >> 3), sc1 = (t & 7) ^ (sj1 & 7);

#define STAGE(off, j0_)                                                        \
  do {                                                                         \
    gl_lds16(Kh + (size_t)((j0_) + sj0) * 64 + sc0 * 8, Klds + (off) + w * 1024); \
    gl_lds16(Kh + (size_t)((j0_) + sj1) * 64 + sc1 * 8,                        \
             Klds + (off) + 4096 + w * 1024);                                  \
    gl_lds16(Vh + (size_t)sj0 * 2048 + (j0_) + sc0 * 8, Vlds + (off) + w * 1024); \
    gl_lds16(Vh + (size_t)sj1 * 2048 + (j0_) + sc1 * 8,                        \
             Vlds + (off) + 4096 + w * 1024);                                  \
  } while (0)

  int jbase = jh * 16;
  int cur = 0;
  STAGE(0, jbase * 64);
  WAITVM0;
  __builtin_amdgcn_s_barrier();
  __builtin_amdgcn_sched_barrier(0);

  for (int jt = 0; jt < 16; ++jt) {
    if (jt < 15) STAGE((cur ^ 1) * 8192, (jbase + jt + 1) * 64);
    const char* Kc = Klds + cur * 8192;
    const char* Vc = Vlds + cur * 8192;

    f32x16 sfr0 = {}, sfr1 = {};
#pragma unroll
    for (int dk = 0; dk < 4; ++dk) {
      int sw = ((dk * 32 + hi * 16) ^ ((col & 7) << 4));
      bf16x8 kf0 = *(const bf16x8*)(Kc + col * 128 + sw);
      bf16x8 kf1 = *(const bf16x8*)(Kc + (32 + col) * 128 + sw);
      sfr0 = mfma32(kf0, qf[dk], sfr0);
      sfr1 = mfma32(kf1, qf[dk], sfr1);
    }

    float psum = 0.f;
    bf16x8 pfr[4];
#pragma unroll
    for (int jk = 0; jk < 4; ++jk) {
      float p[8];
#pragma unroll
      for (int c = 0; c < 8; ++c) {
        float sv = (jk < 2) ? sfr0[(jk & 1) * 8 + c] : sfr1[(jk & 1) * 8 + c];
        p[c] = __builtin_amdgcn_exp2f(sv * K1);
      }
      psum += ((p[0] + p[1]) + (p[2] + p[3])) + ((p[4] + p[5]) + (p[6] + p[7]));
      unsigned X0 = cvtpk_bf16(p[0], p[1]);
      unsigned X1 = cvtpk_bf16(p[2], p[3]);
      unsigned Y0 = cvtpk_bf16(p[4], p[5]);
      unsigned Y1 = cvtpk_bf16(p[6], p[7]);
      pl32swap(X0, Y0);
      pl32swap(X1, Y1);
      union { unsigned u[4]; bf16x8 v; } pu;
      pu.u[0] = X0; pu.u[1] = X1; pu.u[2] = Y0; pu.u[3] = Y1;
      pfr[jk] = pu.v;
    }
    l_run += psum;

#pragma unroll
    for (int jk = 0; jk < 4; ++jk) {
      int sw = ((jk * 32 + hi * 16) ^ ((col & 7) << 4));
      bf16x8 vf0 = *(const bf16x8*)(Vc + col * 128 + sw);
      bf16x8 vf1 = *(const bf16x8*)(Vc + (32 + col) * 128 + sw);
      oacc0 = mfma32(vf0, pfr[jk], oacc0);
      oacc1 = mfma32(vf1, pfr[jk], oacc1);
    }

    WAITVM0;
    __builtin_amdgcn_s_barrier();
    __builtin_amdgcn_sched_barrier(0);
    cur ^= 1;
  }
#undef STAGE

  l_run += __shfl_xor(l_run, 32);
  float linv = 1.0f / l_run;
  if (hi == 0)
    lbuf[(((size_t)bh * 16 + blockIdx.x) * 2 + jh) * 128 + w * 32 + col] = l_run;

  char* Ow = Klds + w * 4096;  // [32 i][128B d-row], swizzled
#pragma unroll
  for (int da = 0; da < 2; ++da) {
    const f32x16& oa = da ? oacc1 : oacc0;
#pragma unroll
    for (int g = 0; g < 4; ++g) {
      unsigned w0 = cvtpk_bf16(oa[g * 4 + 0] * linv, oa[g * 4 + 1] * linv);
      unsigned w1 = cvtpk_bf16(oa[g * 4 + 2] * linv, oa[g * 4 + 3] * linv);
      int dby = da * 64 + g * 16 + hi * 8;
      char* dst = Ow + col * 128 + ((dby & ~15) ^ ((col & 7) << 4)) + (dby & 8);
      u32x2 pr = {w0, w1};
      *(u32x2*)dst = pr;
    }
  }
  int rr0 = ln >> 3, c16o = ln & 7;
#pragma unroll
  for (int pp = 0; pp < 4; ++pp) {
    int rr = rr0 + pp * 8;
    bf16x8 ov = *(const bf16x8*)(Ow + rr * 128 + ((c16o * 16) ^ ((rr & 7) << 4)));
    int grow = bq * 2048 + q0 + w * 32 + rr;
    *(bf16x8*)(Oh + (size_t)grow * 1024 + h * 64 + c16o * 8) = ov;
  }
}

// ------------------------------------------------------------- combine
// vectorized — 8 elems (16B)/thread, grid 2048x256 (r12-verified).
__global__ __launch_bounds__(256) void combine_kernel(
    __bf16* __restrict__ O0, const __bf16* __restrict__ O1,
    const float* __restrict__ lbuf) {
  int idx = blockIdx.x * 256 + threadIdx.x;
  int e0 = idx * 8;
  int r = e0 >> 10, c0 = e0 & 1023;
  int b = r >> 11, seq = r & 2047, qb = seq >> 7, i = seq & 127;
  int h = c0 >> 6;
  int bh = b * 16 + h;
  size_t lbase = (((size_t)bh * 16 + qb) * 2) * 128 + i;
  float l0 = lbuf[lbase], l1 = lbuf[lbase + 128];
  float inv = 1.0f / (l0 + l1);
  float w0 = l0 * inv, w1 = l1 * inv;
  bf16x8 a = *(const bf16x8*)(O0 + e0);
  bf16x8 bb = *(const bf16x8*)(O1 + e0);
  unsigned u[4];
#pragma unroll
  for (int j = 0; j < 4; ++j) {
    float lo = w0 * bf16_f32(a[2 * j]) + w1 * bf16_f32(bb[2 * j]);
    float hi2 = w0 * bf16_f32(a[2 * j + 1]) + w1 * bf16_f32(bb[2 * j + 1]);
    u[j] = cvtpk_bf16(lo, hi2);
  }
  union { unsigned uu[4]; bf16x8 v; } pu;
  pu.uu[0] = u[0]; pu.uu[1] = u[1]; pu.uu[2] = u[2]; pu.uu[3] = u[3];
  *(bf16x8*)(O0 + e0) = pu.v;
}

// ---------------------------------------------------------------- launch
extern "C" void kernel_launch(void* const* d_in, const int* in_sizes, int n_in,
                              void* d_out, int out_size, void* d_ws, size_t ws_size,
                              hipStream_t stream) {
  const float* x = (const float*)d_in[0];
  const float* gamma = (const float*)d_in[1];
  const float* beta = (const float*)d_in[2];
  const float* w_qkv = (const float*)d_in[3];
  const float* w_out = (const float*)d_in[4];
  const float* b_out = (const float*)d_in[5];

  char* ws = (char*)d_ws;
  // [0..8): xn / attn half-0 partial / final sa (in-place combine)
  // [8..16): attn half-1 partial
  // [16..22): wqkvT (dead after QKV GEMM; first 1MB reused as lbuf by attn)
  // [22..24): woutT
  // [24..32): Qb   [32..40): Kb   [40..48): VTb
  __bf16* xn = (__bf16*)(ws);
  __bf16* Opart = xn;                               // halves at +0MB / +8MB
  float* lbuf = (float*)(ws + (16l << 20));
  __bf16* wqkvT = (__bf16*)(ws + (16l << 20));
  __bf16* woutT = (__bf16*)(ws + (22l << 20));
  __bf16* Qb = (__bf16*)(ws + (24l << 20));
  __bf16* Kb = (__bf16*)(ws + (32l << 20));
  __bf16* VTb = (__bf16*)(ws + (40l << 20));
  __bf16* sa = xn;  // combine merges half-1 into half-0 in place

  prep_kernel<<<5120, 256, 0, stream>>>(x, gamma, beta, xn, w_qkv, wqkvT,
                                        w_out, woutT);
  gemm_qkv_kernel<<<dim3(24, 32), 256, 0, stream>>>(xn, wqkvT, Qb, Kb, VTb);
  attn_kernel<<<dim3(16, 32, 2), 256, 0, stream>>>(Qb, Kb, VTb, Opart, lbuf);
  combine_kernel<<<2048, 256, 0, stream>>>(sa, Opart + (4096l * 1024), lbuf);
  gemm_out_kernel<<<dim3(16, 32), 256, 0, stream>>>(sa, woutT, (float*)d_out, b_out);
}

// Round 14
// 133.234 us; speedup vs baseline: 1.0028x; 1.0028x over previous
//
#include <hip/hip_runtime.h>

typedef __attribute__((ext_vector_type(4))) float f32x4;
typedef __attribute__((ext_vector_type(16))) float f32x16;
typedef __attribute__((ext_vector_type(8))) __bf16 bf16x8;
typedef __attribute__((ext_vector_type(4))) unsigned short u16x4;
typedef __attribute__((ext_vector_type(2))) unsigned int u32x2;

#define DEVI static __device__ __forceinline__

DEVI unsigned short bf16_bits(float f) {
  __bf16 h = (__bf16)f;
  return __builtin_bit_cast(unsigned short, h);
}

DEVI float bf16_f32(__bf16 u) { return (float)u; }

DEVI void gl_lds16(const void* g, void* l) {
  __builtin_amdgcn_global_load_lds(
      (const __attribute__((address_space(1))) void*)g,
      (__attribute__((address_space(3))) void*)l, 16, 0, 0);
}

DEVI f32x4 mfma16x16(bf16x8 a, bf16x8 b, f32x4 c) {
  return __builtin_amdgcn_mfma_f32_16x16x32_bf16(a, b, c, 0, 0, 0);
}

DEVI f32x16 mfma32(bf16x8 a, bf16x8 b, f32x16 c) {
  return __builtin_amdgcn_mfma_f32_32x32x16_bf16(a, b, c, 0, 0, 0);
}

DEVI unsigned cvtpk_bf16(float lo, float hi2) {
  unsigned r;
  asm("v_cvt_pk_bf16_f32 %0, %1, %2" : "=v"(r) : "v"(lo), "v"(hi2));
  return r;
}

// NOTE (r3/r4 lesson): never call with two copies of the same value — the
// allocator may coalesce them into ONE register and the swap degenerates.
DEVI void pl32swap(unsigned& a, unsigned& b) {
  asm volatile("s_nop 1\nv_permlane32_swap_b32 %0, %1\ns_nop 1"
               : "+v"(a), "+v"(b));
}

#define WAITVM0 asm volatile("s_waitcnt vmcnt(0)" ::: "memory")

// ---------------------------------------------------------------- prep
// fused ln (blocks 0..4095) + w_qkv transpose (4096..4863) + w_out
// transpose (4864..5119). r13-verified.
__global__ __launch_bounds__(256) void prep_kernel(
    const float* __restrict__ x, const float* __restrict__ gamma,
    const float* __restrict__ beta, __bf16* __restrict__ xn,
    const float* __restrict__ w_qkv, __bf16* __restrict__ wqkvT,
    const float* __restrict__ w_out, __bf16* __restrict__ woutT) {
  __shared__ float tile[64][65];
  __shared__ float red[8];
  int blk = blockIdx.x;
  int t = threadIdx.x;
  if (blk < 4096) {
    int row = blk;
    float4 v = ((const float4*)(x + (size_t)row * 1024))[t];
    float s = v.x + v.y + v.z + v.w;
    float sq = v.x * v.x + v.y * v.y + v.z * v.z + v.w * v.w;
#pragma unroll
    for (int off = 32; off > 0; off >>= 1) {
      s += __shfl_down(s, off);
      sq += __shfl_down(sq, off);
    }
    int w = t >> 6, ln = t & 63;
    if (ln == 0) { red[w] = s; red[4 + w] = sq; }
    __syncthreads();
    s = red[0] + red[1] + red[2] + red[3];
    sq = red[4] + red[5] + red[6] + red[7];
    float mu = s * (1.0f / 1024.0f);
    float var = sq * (1.0f / 1024.0f) - mu * mu;
    float rstd = rsqrtf(var + 1e-5f);
    float4 g = ((const float4*)gamma)[t];
    float4 b = ((const float4*)beta)[t];
    u16x4 o;
    o[0] = bf16_bits((v.x - mu) * rstd * g.x + b.x);
    o[1] = bf16_bits((v.y - mu) * rstd * g.y + b.y);
    o[2] = bf16_bits((v.z - mu) * rstd * g.z + b.z);
    o[3] = bf16_bits((v.w - mu) * rstd * g.w + b.w);
    *(u16x4*)(xn + (size_t)row * 1024 + t * 4) = o;
    return;
  }
  const float* in;
  __bf16* out;
  int R, C, bx, by;
  if (blk < 4096 + 768) {
    int i2 = blk - 4096;
    in = w_qkv; out = wqkvT; R = 1024; C = 3072;
    bx = i2 % 48; by = i2 / 48;
  } else {
    int i3 = blk - 4864;
    in = w_out; out = woutT; R = 1024; C = 1024;
    bx = i3 % 16; by = i3 / 16;
  }
  int tx = t & 15, ty = t >> 4;
  int c0 = bx * 64, r0 = by * 64;
#pragma unroll
  for (int p = 0; p < 4; ++p) {
    int r = ty + p * 16;
    float4 v = *(const float4*)(in + (size_t)(r0 + r) * C + c0 + tx * 4);
    tile[r][tx * 4 + 0] = v.x;
    tile[r][tx * 4 + 1] = v.y;
    tile[r][tx * 4 + 2] = v.z;
    tile[r][tx * 4 + 3] = v.w;
  }
  __syncthreads();
#pragma unroll
  for (int p = 0; p < 4; ++p) {
    int cc = ty + p * 16;
    u16x4 o;
    o[0] = bf16_bits(tile[tx * 4 + 0][cc]);
    o[1] = bf16_bits(tile[tx * 4 + 1][cc]);
    o[2] = bf16_bits(tile[tx * 4 + 2][cc]);
    o[3] = bf16_bits(tile[tx * 4 + 3][cc]);
    *(u16x4*)(out + (size_t)(c0 + cc) * R + r0 + tx * 4) = o;
  }
}

// ---------------------------------------------------------------- QK GEMM
// Round-14: swapped orientation ONLY (r13-verified values), isolated so the
// register allocator carries one MFMA path. n0 in [0,2048): Q and K.
// Per-lane acc = 4 consecutive d at fixed seq -> one u16x4 store.
__global__ __launch_bounds__(256) void gemm_qk_kernel(
    const __bf16* __restrict__ A, const __bf16* __restrict__ BT,
    __bf16* __restrict__ Qb, __bf16* __restrict__ Kb) {
  __shared__ __align__(16) __bf16 Asm[128 * 32];
  __shared__ __align__(16) __bf16 Bsm[128 * 32];
  const int KD = 1024;
  int t = threadIdx.x;
  int w = t >> 6, ln = t & 63;
  int wr = w >> 1, wc = w & 1;
  int m0 = blockIdx.y * 128, n0 = blockIdx.x * 128;
  f32x4 acc[4][4] = {};

  int srow = w * 16 + (ln >> 2);
  int scol = (ln & 3) * 8;
  int lrow = ln & 15;
  int lkb = (ln >> 4) * 16;

  for (int kk = 0; kk < KD; kk += 32) {
    __syncthreads();
#pragma unroll
    for (int i = 0; i < 2; ++i) {
      int row = i * 64 + srow;
      gl_lds16(A + (size_t)(m0 + row) * KD + kk + scol,
               (char*)Asm + i * 4096 + w * 1024);
      gl_lds16(BT + (size_t)(n0 + row) * KD + kk + scol,
               (char*)Bsm + i * 4096 + w * 1024);
    }
    __syncthreads();
    bf16x8 af[4], bfr[4];
#pragma unroll
    for (int mi = 0; mi < 4; ++mi)
      af[mi] = *(const bf16x8*)((char*)Asm + (wr * 64 + mi * 16 + lrow) * 64 + lkb);
#pragma unroll
    for (int ni = 0; ni < 4; ++ni)
      bfr[ni] = *(const bf16x8*)((char*)Bsm + (wc * 64 + ni * 16 + lrow) * 64 + lkb);
#pragma unroll
    for (int mi = 0; mi < 4; ++mi)
#pragma unroll
      for (int ni = 0; ni < 4; ++ni)
        acc[mi][ni] = mfma16x16(bfr[ni], af[mi], acc[mi][ni]);  // swapped
  }

  int r4 = (ln >> 4) * 4;
#pragma unroll
  for (int mi = 0; mi < 4; ++mi) {
#pragma unroll
    for (int ni = 0; ni < 4; ++ni) {
      int seq_g = m0 + wr * 64 + mi * 16 + lrow;
      int nfeat = n0 + wc * 64 + ni * 16 + r4;  // 4 consecutive n
      int sel = nfeat >> 10;                    // 0=Q 1=K
      int nl = nfeat & 1023;
      int h = nl >> 6, d0 = nl & 63;
      int b = seq_g >> 11, seq = seq_g & 2047;
      int bh = b * 16 + h;
      __bf16* dst = (sel == 0 ? Qb : Kb);
      u16x4 o;
      o[0] = bf16_bits(acc[mi][ni][0]);
      o[1] = bf16_bits(acc[mi][ni][1]);
      o[2] = bf16_bits(acc[mi][ni][2]);
      o[3] = bf16_bits(acc[mi][ni][3]);
      *(u16x4*)(dst + ((size_t)bh * 2048 + seq) * 64 + d0) = o;
    }
  }
}

// ---------------------------------------------------------------- V GEMM
// Round-14: normal orientation ONLY, BM=128 x BN=64 (gemm_out skeleton) ->
// grid (16,32) = 512 blocks = 2/CU (was 256 = 1/CU). VT epilogue: per-lane
// 4 consecutive seq at fixed d -> one u16x4 store (r13-verified path).
__global__ __launch_bounds__(256) void gemm_v_kernel(
    const __bf16* __restrict__ A, const __bf16* __restrict__ BT,
    __bf16* __restrict__ VTb) {
  __shared__ __align__(16) __bf16 Asm[128 * 32];  // 8KB
  __shared__ __align__(16) __bf16 Bsm[64 * 32];   // 4KB
  const int KD = 1024;
  int t = threadIdx.x;
  int w = t >> 6, ln = t & 63;
  int m0 = blockIdx.y * 128, n0 = 2048 + blockIdx.x * 64;
  f32x4 acc[2][4] = {};

  int srow = w * 16 + (ln >> 2);  // 0..63
  int scol = (ln & 3) * 8;
  int lrow = ln & 15;
  int lkb = (ln >> 4) * 16;

  for (int kk = 0; kk < KD; kk += 32) {
    __syncthreads();
#pragma unroll
    for (int i = 0; i < 2; ++i)
      gl_lds16(A + (size_t)(m0 + i * 64 + srow) * KD + kk + scol,
               (char*)Asm + i * 4096 + w * 1024);
    gl_lds16(BT + (size_t)(n0 + srow) * KD + kk + scol, (char*)Bsm + w * 1024);
    __syncthreads();
    bf16x8 af[2], bfr[4];
#pragma unroll
    for (int mi = 0; mi < 2; ++mi)
      af[mi] = *(const bf16x8*)((char*)Asm + (w * 32 + mi * 16 + lrow) * 64 + lkb);
#pragma unroll
    for (int ni = 0; ni < 4; ++ni)
      bfr[ni] = *(const bf16x8*)((char*)Bsm + (ni * 16 + lrow) * 64 + lkb);
#pragma unroll
    for (int mi = 0; mi < 2; ++mi)
#pragma unroll
      for (int ni = 0; ni < 4; ++ni)
        acc[mi][ni] = mfma16x16(af[mi], bfr[ni], acc[mi][ni]);  // normal
  }

  int r4 = (ln >> 4) * 4;
#pragma unroll
  for (int mi = 0; mi < 2; ++mi) {
#pragma unroll
    for (int ni = 0; ni < 4; ++ni) {
      int grow = m0 + w * 32 + mi * 16 + r4;    // 4 consecutive seq
      int gcol = n0 + ni * 16 + lrow;
      int nl = gcol & 1023;
      int h = nl >> 6, d = nl & 63;
      int b = grow >> 11, seq = grow & 2047;
      int bh = b * 16 + h;
      u16x4 o;
      o[0] = bf16_bits(acc[mi][ni][0]);
      o[1] = bf16_bits(acc[mi][ni][1]);
      o[2] = bf16_bits(acc[mi][ni][2]);
      o[3] = bf16_bits(acc[mi][ni][3]);
      *(u16x4*)(VTb + ((size_t)bh * 64 + d) * 2048 + seq) = o;
    }
  }
}

// ---------------------------------------------------------------- out GEMM
// r13-verified: swapped orientation -> float4 C store + float4 bias load.
__global__ __launch_bounds__(256) void gemm_out_kernel(
    const __bf16* __restrict__ A, const __bf16* __restrict__ BT,
    float* __restrict__ Cout, const float* __restrict__ bias) {
  __shared__ __align__(16) __bf16 Asm[128 * 32];  // 8KB
  __shared__ __align__(16) __bf16 Bsm[64 * 32];   // 4KB
  const int KD = 1024;
  int t = threadIdx.x;
  int w = t >> 6, ln = t & 63;
  int m0 = blockIdx.y * 128, n0 = blockIdx.x * 64;
  f32x4 acc[2][4] = {};

  int srow = w * 16 + (ln >> 2);
  int scol = (ln & 3) * 8;
  int lrow = ln & 15;
  int lkb = (ln >> 4) * 16;

  for (int kk = 0; kk < KD; kk += 32) {
    __syncthreads();
#pragma unroll
    for (int i = 0; i < 2; ++i)
      gl_lds16(A + (size_t)(m0 + i * 64 + srow) * KD + kk + scol,
               (char*)Asm + i * 4096 + w * 1024);
    gl_lds16(BT + (size_t)(n0 + srow) * KD + kk + scol, (char*)Bsm + w * 1024);
    __syncthreads();
    bf16x8 af[2], bfr[4];
#pragma unroll
    for (int mi = 0; mi < 2; ++mi)
      af[mi] = *(const bf16x8*)((char*)Asm + (w * 32 + mi * 16 + lrow) * 64 + lkb);
#pragma unroll
    for (int ni = 0; ni < 4; ++ni)
      bfr[ni] = *(const bf16x8*)((char*)Bsm + (ni * 16 + lrow) * 64 + lkb);
#pragma unroll
    for (int mi = 0; mi < 2; ++mi)
#pragma unroll
      for (int ni = 0; ni < 4; ++ni)
        acc[mi][ni] = mfma16x16(bfr[ni], af[mi], acc[mi][ni]);  // swapped
  }

  int r4 = (ln >> 4) * 4;
#pragma unroll
  for (int mi = 0; mi < 2; ++mi) {
#pragma unroll
    for (int ni = 0; ni < 4; ++ni) {
      int m = m0 + w * 32 + mi * 16 + lrow;
      int nb = n0 + ni * 16 + r4;
      float4 bv = *(const float4*)(bias + nb);
      float4 o;
      o.x = acc[mi][ni][0] + bv.x;
      o.y = acc[mi][ni][1] + bv.y;
      o.z = acc[mi][ni][2] + bv.z;
      o.w = acc[mi][ni][3] + bv.w;
      *(float4*)(Cout + (size_t)m * 1024 + nb) = o;
    }
  }
}

// ---------------------------------------------------------------- attention
// r11-verified: j-SPLIT flash (exact under no-max softmax), grid (16,32,2).
__global__ __launch_bounds__(256, 2) void attn_kernel(
    const __bf16* __restrict__ Qb, const __bf16* __restrict__ Kb,
    const __bf16* __restrict__ VTb, __bf16* __restrict__ Opart,
    float* __restrict__ lbuf) {
  __shared__ __align__(16) char Klds[16384];   // 2 bufs x [64 j][128B], swizzled
  __shared__ __align__(16) char Vlds[16384];   // 2 bufs x [64 d][128B], swizzled
  const float LOG2E = 1.44269504f;
  const float K1 = 0.125f * LOG2E;
  int t = threadIdx.x, w = t >> 6, ln = t & 63;
  int hi = ln >> 5, col = ln & 31;
  int bh = blockIdx.y, bq = bh >> 4, h = bh & 15;
  int q0 = blockIdx.x * 128;
  int jh = blockIdx.z;
  const __bf16* Qh = Qb + (size_t)bh * 2048 * 64;
  const __bf16* Kh = Kb + (size_t)bh * 2048 * 64;
  const __bf16* Vh = VTb + (size_t)bh * 64 * 2048;
  __bf16* Oh = Opart + (size_t)jh * 4096 * 1024;

  bf16x8 qf[4];
  int qrow = q0 + w * 32 + col;
#pragma unroll
  for (int dk = 0; dk < 4; ++dk)
    qf[dk] = *(const bf16x8*)(Qh + (size_t)qrow * 64 + dk * 16 + hi * 8);

  f32x16 oacc0 = {}, oacc1 = {};
  float l_run = 0.f;

  int sj0 = t >> 3, sc0 = (t & 7) ^ (sj0 & 7);
  int sj1 = 32 + (t >> 3), sc1 = (t & 7) ^ (sj1 & 7);

#define STAGE(off, j0_)                                                        \
  do {                                                                         \
    gl_lds16(Kh + (size_t)((j0_) + sj0) * 64 + sc0 * 8, Klds + (off) + w * 1024); \
    gl_lds16(Kh + (size_t)((j0_) + sj1) * 64 + sc1 * 8,                        \
             Klds + (off) + 4096 + w * 1024);                                  \
    gl_lds16(Vh + (size_t)sj0 * 2048 + (j0_) + sc0 * 8, Vlds + (off) + w * 1024); \
    gl_lds16(Vh + (size_t)sj1 * 2048 + (j0_) + sc1 * 8,                        \
             Vlds + (off) + 4096 + w * 1024);                                  \
  } while (0)

  int jbase = jh * 16;
  int cur = 0;
  STAGE(0, jbase * 64);
  WAITVM0;
  __builtin_amdgcn_s_barrier();
  __builtin_amdgcn_sched_barrier(0);

  for (int jt = 0; jt < 16; ++jt) {
    if (jt < 15) STAGE((cur ^ 1) * 8192, (jbase + jt + 1) * 64);
    const char* Kc = Klds + cur * 8192;
    const char* Vc = Vlds + cur * 8192;

    f32x16 sfr0 = {}, sfr1 = {};
#pragma unroll
    for (int dk = 0; dk < 4; ++dk) {
      int sw = ((dk * 32 + hi * 16) ^ ((col & 7) << 4));
      bf16x8 kf0 = *(const bf16x8*)(Kc + col * 128 + sw);
      bf16x8 kf1 = *(const bf16x8*)(Kc + (32 + col) * 128 + sw);
      sfr0 = mfma32(kf0, qf[dk], sfr0);
      sfr1 = mfma32(kf1, qf[dk], sfr1);
    }

    float psum = 0.f;
    bf16x8 pfr[4];
#pragma unroll
    for (int jk = 0; jk < 4; ++jk) {
      float p[8];
#pragma unroll
      for (int c = 0; c < 8; ++c) {
        float sv = (jk < 2) ? sfr0[(jk & 1) * 8 + c] : sfr1[(jk & 1) * 8 + c];
        p[c] = __builtin_amdgcn_exp2f(sv * K1);
      }
      psum += ((p[0] + p[1]) + (p[2] + p[3])) + ((p[4] + p[5]) + (p[6] + p[7]));
      unsigned X0 = cvtpk_bf16(p[0], p[1]);
      unsigned X1 = cvtpk_bf16(p[2], p[3]);
      unsigned Y0 = cvtpk_bf16(p[4], p[5]);
      unsigned Y1 = cvtpk_bf16(p[6], p[7]);
      pl32swap(X0, Y0);
      pl32swap(X1, Y1);
      union { unsigned u[4]; bf16x8 v; } pu;
      pu.u[0] = X0; pu.u[1] = X1; pu.u[2] = Y0; pu.u[3] = Y1;
      pfr[jk] = pu.v;
    }
    l_run += psum;

#pragma unroll
    for (int jk = 0; jk < 4; ++jk) {
      int sw = ((jk * 32 + hi * 16) ^ ((col & 7) << 4));
      bf16x8 vf0 = *(const bf16x8*)(Vc + col * 128 + sw);
      bf16x8 vf1 = *(const bf16x8*)(Vc + (32 + col) * 128 + sw);
      oacc0 = mfma32(vf0, pfr[jk], oacc0);
      oacc1 = mfma32(vf1, pfr[jk], oacc1);
    }

    WAITVM0;
    __builtin_amdgcn_s_barrier();
    __builtin_amdgcn_sched_barrier(0);
    cur ^= 1;
  }
#undef STAGE

  l_run += __shfl_xor(l_run, 32);
  float linv = 1.0f / l_run;
  if (hi == 0)
    lbuf[(((size_t)bh * 16 + blockIdx.x) * 2 + jh) * 128 + w * 32 + col] = l_run;

  char* Ow = Klds + w * 4096;
#pragma unroll
  for (int da = 0; da < 2; ++da) {
    const f32x16& oa = da ? oacc1 : oacc0;
#pragma unroll
    for (int g = 0; g < 4; ++g) {
      unsigned w0 = cvtpk_bf16(oa[g * 4 + 0] * linv, oa[g * 4 + 1] * linv);
      unsigned w1 = cvtpk_bf16(oa[g * 4 + 2] * linv, oa[g * 4 + 3] * linv);
      int dby = da * 64 + g * 16 + hi * 8;
      char* dst = Ow + col * 128 + ((dby & ~15) ^ ((col & 7) << 4)) + (dby & 8);
      u32x2 pr = {w0, w1};
      *(u32x2*)dst = pr;
    }
  }
  int rr0 = ln >> 3, c16o = ln & 7;
#pragma unroll
  for (int pp = 0; pp < 4; ++pp) {
    int rr = rr0 + pp * 8;
    bf16x8 ov = *(const bf16x8*)(Ow + rr * 128 + ((c16o * 16) ^ ((rr & 7) << 4)));
    int grow = bq * 2048 + q0 + w * 32 + rr;
    *(bf16x8*)(Oh + (size_t)grow * 1024 + h * 64 + c16o * 8) = ov;
  }
}

// ------------------------------------------------------------- combine
// vectorized — 8 elems (16B)/thread, grid 2048x256 (r12-verified).
__global__ __launch_bounds__(256) void combine_kernel(
    __bf16* __restrict__ O0, const __bf16* __restrict__ O1,
    const float* __restrict__ lbuf) {
  int idx = blockIdx.x * 256 + threadIdx.x;
  int e0 = idx * 8;
  int r = e0 >> 10, c0 = e0 & 1023;
  int b = r >> 11, seq = r & 2047, qb = seq >> 7, i = seq & 127;
  int h = c0 >> 6;
  int bh = b * 16 + h;
  size_t lbase = (((size_t)bh * 16 + qb) * 2) * 128 + i;
  float l0 = lbuf[lbase], l1 = lbuf[lbase + 128];
  float inv = 1.0f / (l0 + l1);
  float w0 = l0 * inv, w1 = l1 * inv;
  bf16x8 a = *(const bf16x8*)(O0 + e0);
  bf16x8 bb = *(const bf16x8*)(O1 + e0);
  unsigned u[4];
#pragma unroll
  for (int j = 0; j < 4; ++j) {
    float lo = w0 * bf16_f32(a[2 * j]) + w1 * bf16_f32(bb[2 * j]);
    float hi2 = w0 * bf16_f32(a[2 * j + 1]) + w1 * bf16_f32(bb[2 * j + 1]);
    u[j] = cvtpk_bf16(lo, hi2);
  }
  union { unsigned uu[4]; bf16x8 v; } pu;
  pu.uu[0] = u[0]; pu.uu[1] = u[1]; pu.uu[2] = u[2]; pu.uu[3] = u[3];
  *(bf16x8*)(O0 + e0) = pu.v;
}

// ---------------------------------------------------------------- launch
extern "C" void kernel_launch(void* const* d_in, const int* in_sizes, int n_in,
                              void* d_out, int out_size, void* d_ws, size_t ws_size,
                              hipStream_t stream) {
  const float* x = (const float*)d_in[0];
  const float* gamma = (const float*)d_in[1];
  const float* beta = (const float*)d_in[2];
  const float* w_qkv = (const float*)d_in[3];
  const float* w_out = (const float*)d_in[4];
  const float* b_out = (const float*)d_in[5];

  char* ws = (char*)d_ws;
  // [0..8): xn / attn half-0 partial / final sa (in-place combine)
  // [8..16): attn half-1 partial
  // [16..22): wqkvT (dead after QK/V GEMMs; first 1MB reused as lbuf by attn)
  // [22..24): woutT
  // [24..32): Qb   [32..40): Kb   [40..48): VTb
  __bf16* xn = (__bf16*)(ws);
  __bf16* Opart = xn;                               // halves at +0MB / +8MB
  float* lbuf = (float*)(ws + (16l << 20));
  __bf16* wqkvT = (__bf16*)(ws + (16l << 20));
  __bf16* woutT = (__bf16*)(ws + (22l << 20));
  __bf16* Qb = (__bf16*)(ws + (24l << 20));
  __bf16* Kb = (__bf16*)(ws + (32l << 20));
  __bf16* VTb = (__bf16*)(ws + (40l << 20));
  __bf16* sa = xn;  // combine merges half-1 into half-0 in place

  prep_kernel<<<5120, 256, 0, stream>>>(x, gamma, beta, xn, w_qkv, wqkvT,
                                        w_out, woutT);
  gemm_qk_kernel<<<dim3(16, 32), 256, 0, stream>>>(xn, wqkvT, Qb, Kb);
  gemm_v_kernel<<<dim3(16, 32), 256, 0, stream>>>(xn, wqkvT, VTb);
  attn_kernel<<<dim3(16, 32, 2), 256, 0, stream>>>(Qb, Kb, VTb, Opart, lbuf);
  combine_kernel<<<2048, 256, 0, stream>>>(sa, Opart + (4096l * 1024), lbuf);
  gemm_out_kernel<<<dim3(16, 32), 256, 0, stream>>>(sa, woutT, (float*)d_out, b_out);
}

// Round 17
// 120.167 us; speedup vs baseline: 1.1119x; 1.1087x over previous
//
#include <hip/hip_runtime.h>

typedef __attribute__((ext_vector_type(4))) float f32x4;
typedef __attribute__((ext_vector_type(16))) float f32x16;
typedef __attribute__((ext_vector_type(8))) __bf16 bf16x8;
typedef __attribute__((ext_vector_type(4))) unsigned short u16x4;
typedef __attribute__((ext_vector_type(2))) unsigned int u32x2;

#define DEVI static __device__ __forceinline__

DEVI unsigned short bf16_bits(float f) {
  __bf16 h = (__bf16)f;
  return __builtin_bit_cast(unsigned short, h);
}

DEVI float bf16_f32(__bf16 u) { return (float)u; }

DEVI void gl_lds16(const void* g, void* l) {
  __builtin_amdgcn_global_load_lds(
      (const __attribute__((address_space(1))) void*)g,
      (__attribute__((address_space(3))) void*)l, 16, 0, 0);
}

DEVI f32x4 mfma16x16(bf16x8 a, bf16x8 b, f32x4 c) {
  return __builtin_amdgcn_mfma_f32_16x16x32_bf16(a, b, c, 0, 0, 0);
}

DEVI f32x16 mfma32(bf16x8 a, bf16x8 b, f32x16 c) {
  return __builtin_amdgcn_mfma_f32_32x32x16_bf16(a, b, c, 0, 0, 0);
}

DEVI unsigned cvtpk_bf16(float lo, float hi2) {
  unsigned r;
  asm("v_cvt_pk_bf16_f32 %0, %1, %2" : "=v"(r) : "v"(lo), "v"(hi2));
  return r;
}

// NOTE (r3/r4): never call with two copies of one value (allocator coalesces).
// NOTE (r15/r16): an MFMA whose ONLY inputs are INLINEASM-built fragments
// (ones-MFMA l-sum) produced schedule-dependent wrong results in two
// placements (shielded + sched_barrier-pinned) — abandoned without .s access.
DEVI void pl32swap(unsigned& a, unsigned& b) {
  asm volatile("s_nop 1\nv_permlane32_swap_b32 %0, %1\ns_nop 1"
               : "+v"(a), "+v"(b));
}

#define WAITVM0 asm volatile("s_waitcnt vmcnt(0)" ::: "memory")

// ---------------------------------------------------------------- prep
// Fused ln (blocks 0..4095) + w_qkv transpose (4096..4863) + w_out
// transpose (4864..5119). Correctness-verified in r13 AND r14.
__global__ __launch_bounds__(256) void prep_kernel(
    const float* __restrict__ x, const float* __restrict__ gamma,
    const float* __restrict__ beta, __bf16* __restrict__ xn,
    const float* __restrict__ w_qkv, __bf16* __restrict__ wqkvT,
    const float* __restrict__ w_out, __bf16* __restrict__ woutT) {
  __shared__ float tile[64][65];
  __shared__ float red[8];
  int blk = blockIdx.x;
  int t = threadIdx.x;
  if (blk < 4096) {
    int row = blk;
    float4 v = ((const float4*)(x + (size_t)row * 1024))[t];
    float s = v.x + v.y + v.z + v.w;
    float sq = v.x * v.x + v.y * v.y + v.z * v.z + v.w * v.w;
#pragma unroll
    for (int off = 32; off > 0; off >>= 1) {
      s += __shfl_down(s, off);
      sq += __shfl_down(sq, off);
    }
    int w = t >> 6, ln = t & 63;
    if (ln == 0) { red[w] = s; red[4 + w] = sq; }
    __syncthreads();
    s = red[0] + red[1] + red[2] + red[3];
    sq = red[4] + red[5] + red[6] + red[7];
    float mu = s * (1.0f / 1024.0f);
    float var = sq * (1.0f / 1024.0f) - mu * mu;
    float rstd = rsqrtf(var + 1e-5f);
    float4 g = ((const float4*)gamma)[t];
    float4 b = ((const float4*)beta)[t];
    u16x4 o;
    o[0] = bf16_bits((v.x - mu) * rstd * g.x + b.x);
    o[1] = bf16_bits((v.y - mu) * rstd * g.y + b.y);
    o[2] = bf16_bits((v.z - mu) * rstd * g.z + b.z);
    o[3] = bf16_bits((v.w - mu) * rstd * g.w + b.w);
    *(u16x4*)(xn + (size_t)row * 1024 + t * 4) = o;
    return;
  }
  const float* in;
  __bf16* out;
  int R, C, bx, by;
  if (blk < 4096 + 768) {
    int i2 = blk - 4096;
    in = w_qkv; out = wqkvT; R = 1024; C = 3072;
    bx = i2 % 48; by = i2 / 48;
  } else {
    int i3 = blk - 4864;
    in = w_out; out = woutT; R = 1024; C = 1024;
    bx = i3 % 16; by = i3 / 16;
  }
  int tx = t & 15, ty = t >> 4;
  int c0 = bx * 64, r0 = by * 64;
#pragma unroll
  for (int p = 0; p < 4; ++p) {
    int r = ty + p * 16;
    float4 v = *(const float4*)(in + (size_t)(r0 + r) * C + c0 + tx * 4);
    tile[r][tx * 4 + 0] = v.x;
    tile[r][tx * 4 + 1] = v.y;
    tile[r][tx * 4 + 2] = v.z;
    tile[r][tx * 4 + 3] = v.w;
  }
  __syncthreads();
#pragma unroll
  for (int p = 0; p < 4; ++p) {
    int cc = ty + p * 16;
    u16x4 o;
    o[0] = bf16_bits(tile[tx * 4 + 0][cc]);
    o[1] = bf16_bits(tile[tx * 4 + 1][cc]);
    o[2] = bf16_bits(tile[tx * 4 + 2][cc]);
    o[3] = bf16_bits(tile[tx * 4 + 3][cc]);
    *(u16x4*)(out + (size_t)(c0 + cc) * R + r0 + tx * 4) = o;
  }
}

// ---------------------------------------------------------------- QKV GEMM
// r12-verified: 128x128 tile, normal orientation, grid (24,32).
__global__ __launch_bounds__(256) void gemm_qkv_kernel(
    const __bf16* __restrict__ A, const __bf16* __restrict__ BT,
    __bf16* __restrict__ Qb, __bf16* __restrict__ Kb, __bf16* __restrict__ VTb) {
  __shared__ __align__(16) __bf16 Asm[128 * 32];
  __shared__ __align__(16) __bf16 Bsm[128 * 32];
  const int KD = 1024;
  int t = threadIdx.x;
  int w = t >> 6, ln = t & 63;
  int wr = w >> 1, wc = w & 1;
  int m0 = blockIdx.y * 128, n0 = blockIdx.x * 128;
  f32x4 acc[4][4] = {};

  int srow = w * 16 + (ln >> 2);
  int scol = (ln & 3) * 8;
  int lrow = ln & 15;
  int lkb = (ln >> 4) * 16;

  for (int kk = 0; kk < KD; kk += 32) {
    __syncthreads();
#pragma unroll
    for (int i = 0; i < 2; ++i) {
      int row = i * 64 + srow;
      gl_lds16(A + (size_t)(m0 + row) * KD + kk + scol,
               (char*)Asm + i * 4096 + w * 1024);
      gl_lds16(BT + (size_t)(n0 + row) * KD + kk + scol,
               (char*)Bsm + i * 4096 + w * 1024);
    }
    __syncthreads();
    bf16x8 af[4], bfr[4];
#pragma unroll
    for (int mi = 0; mi < 4; ++mi)
      af[mi] = *(const bf16x8*)((char*)Asm + (wr * 64 + mi * 16 + lrow) * 64 + lkb);
#pragma unroll
    for (int ni = 0; ni < 4; ++ni)
      bfr[ni] = *(const bf16x8*)((char*)Bsm + (wc * 64 + ni * 16 + lrow) * 64 + lkb);
#pragma unroll
    for (int mi = 0; mi < 4; ++mi)
#pragma unroll
      for (int ni = 0; ni < 4; ++ni)
        acc[mi][ni] = mfma16x16(af[mi], bfr[ni], acc[mi][ni]);
  }

  int r4 = (ln >> 4) * 4;
#pragma unroll
  for (int mi = 0; mi < 4; ++mi) {
#pragma unroll
    for (int ni = 0; ni < 4; ++ni) {
      int grow = m0 + wr * 64 + mi * 16 + r4;
      int gcol = n0 + wc * 64 + ni * 16 + lrow;
      int sel = gcol >> 10;
      int nl = gcol & 1023;
      int h = nl >> 6, d = nl & 63;
      int b = grow >> 11, seq = grow & 2047;
      int bh = b * 16 + h;
      if (sel < 2) {
        __bf16* dst = (sel == 0 ? Qb : Kb) + ((size_t)bh * 2048 + seq) * 64 + d;
#pragma unroll
        for (int r = 0; r < 4; ++r) dst[(size_t)r * 64] = (__bf16)acc[mi][ni][r];
      } else {
        u16x4 o;
        o[0] = bf16_bits(acc[mi][ni][0]);
        o[1] = bf16_bits(acc[mi][ni][1]);
        o[2] = bf16_bits(acc[mi][ni][2]);
        o[3] = bf16_bits(acc[mi][ni][3]);
        *(u16x4*)(VTb + ((size_t)bh * 64 + d) * 2048 + seq) = o;
      }
    }
  }
}

// ---------------------------------------------------------------- out GEMM
// r12-verified: BM=128 x BN=64, normal orientation, grid (16,32).
__global__ __launch_bounds__(256) void gemm_out_kernel(
    const __bf16* __restrict__ A, const __bf16* __restrict__ BT,
    float* __restrict__ Cout, const float* __restrict__ bias) {
  __shared__ __align__(16) __bf16 Asm[128 * 32];  // 8KB
  __shared__ __align__(16) __bf16 Bsm[64 * 32];   // 4KB
  const int KD = 1024;
  int t = threadIdx.x;
  int w = t >> 6, ln = t & 63;
  int m0 = blockIdx.y * 128, n0 = blockIdx.x * 64;
  f32x4 acc[2][4] = {};

  int srow = w * 16 + (ln >> 2);  // 0..63
  int scol = (ln & 3) * 8;
  int lrow = ln & 15;
  int lkb = (ln >> 4) * 16;

  for (int kk = 0; kk < KD; kk += 32) {
    __syncthreads();
#pragma unroll
    for (int i = 0; i < 2; ++i)
      gl_lds16(A + (size_t)(m0 + i * 64 + srow) * KD + kk + scol,
               (char*)Asm + i * 4096 + w * 1024);
    gl_lds16(BT + (size_t)(n0 + srow) * KD + kk + scol, (char*)Bsm + w * 1024);
    __syncthreads();
    bf16x8 af[2], bfr[4];
#pragma unroll
    for (int mi = 0; mi < 2; ++mi)
      af[mi] = *(const bf16x8*)((char*)Asm + (w * 32 + mi * 16 + lrow) * 64 + lkb);
#pragma unroll
    for (int ni = 0; ni < 4; ++ni)
      bfr[ni] = *(const bf16x8*)((char*)Bsm + (ni * 16 + lrow) * 64 + lkb);
#pragma unroll
    for (int mi = 0; mi < 2; ++mi)
#pragma unroll
      for (int ni = 0; ni < 4; ++ni)
        acc[mi][ni] = mfma16x16(af[mi], bfr[ni], acc[mi][ni]);
  }

  int r4 = (ln >> 4) * 4;
#pragma unroll
  for (int mi = 0; mi < 2; ++mi) {
#pragma unroll
    for (int ni = 0; ni < 4; ++ni) {
      int grow = m0 + w * 32 + mi * 16 + r4;
      int gcol = n0 + ni * 16 + lrow;
      float bv = bias[gcol];
#pragma unroll
      for (int r = 0; r < 4; ++r)
        Cout[(size_t)(grow + r) * 1024 + gcol] = acc[mi][ni][r] + bv;
    }
  }
}

// ---------------------------------------------------------------- attention
// r11/r12-verified: j-SPLIT flash (exact under no-max softmax), grid (16,32,2).
__global__ __launch_bounds__(256, 2) void attn_kernel(
    const __bf16* __restrict__ Qb, const __bf16* __restrict__ Kb,
    const __bf16* __restrict__ VTb, __bf16* __restrict__ Opart,
    float* __restrict__ lbuf) {
  __shared__ __align__(16) char Klds[16384];   // 2 bufs x [64 j][128B], swizzled
  __shared__ __align__(16) char Vlds[16384];   // 2 bufs x [64 d][128B], swizzled
  const float LOG2E = 1.44269504f;
  const float K1 = 0.125f * LOG2E;
  int t = threadIdx.x, w = t >> 6, ln = t & 63;
  int hi = ln >> 5, col = ln & 31;
  int bh = blockIdx.y, bq = bh >> 4, h = bh & 15;
  int q0 = blockIdx.x * 128;
  int jh = blockIdx.z;                 // j-half: tiles jh*16 .. jh*16+15
  const __bf16* Qh = Qb + (size_t)bh * 2048 * 64;
  const __bf16* Kh = Kb + (size_t)bh * 2048 * 64;
  const __bf16* Vh = VTb + (size_t)bh * 64 * 2048;
  __bf16* Oh = Opart + (size_t)jh * 4096 * 1024;  // half = 4M bf16 = 8MB

  bf16x8 qf[4];
  int qrow = q0 + w * 32 + col;
#pragma unroll
  for (int dk = 0; dk < 4; ++dk)
    qf[dk] = *(const bf16x8*)(Qh + (size_t)qrow * 64 + dk * 16 + hi * 8);

  f32x16 oacc0 = {}, oacc1 = {};
  float l_run = 0.f;

  int sj0 = t >> 3, sc0 = (t & 7) ^ (sj0 & 7);
  int sj1 = 32 + (t >> 3), sc1 = (t & 7) ^ (sj1 & 7);

#define STAGE(off, j0_)                                                        \
  do {                                                                         \
    gl_lds16(Kh + (size_t)((j0_) + sj0) * 64 + sc0 * 8, Klds + (off) + w * 1024); \
    gl_lds16(Kh + (size_t)((j0_) + sj1) * 64 + sc1 * 8,                        \
             Klds + (off) + 4096 + w * 1024);                                  \
    gl_lds16(Vh + (size_t)sj0 * 2048 + (j0_) + sc0 * 8, Vlds + (off) + w * 1024); \
    gl_lds16(Vh + (size_t)sj1 * 2048 + (j0_) + sc1 * 8,                        \
             Vlds + (off) + 4096 + w * 1024);                                  \
  } while (0)

  int jbase = jh * 16;
  int cur = 0;
  STAGE(0, jbase * 64);
  WAITVM0;
  __builtin_amdgcn_s_barrier();
  __builtin_amdgcn_sched_barrier(0);

  for (int jt = 0; jt < 16; ++jt) {
    if (jt < 15) STAGE((cur ^ 1) * 8192, (jbase + jt + 1) * 64);
    const char* Kc = Klds + cur * 8192;
    const char* Vc = Vlds + cur * 8192;

    f32x16 sfr0 = {}, sfr1 = {};
#pragma unroll
    for (int dk = 0; dk < 4; ++dk) {
      int sw = ((dk * 32 + hi * 16) ^ ((col & 7) << 4));
      bf16x8 kf0 = *(const bf16x8*)(Kc + col * 128 + sw);
      bf16x8 kf1 = *(const bf16x8*)(Kc + (32 + col) * 128 + sw);
      sfr0 = mfma32(kf0, qf[dk], sfr0);
      sfr1 = mfma32(kf1, qf[dk], sfr1);
    }

    float psum = 0.f;
    bf16x8 pfr[4];
#pragma unroll
    for (int jk = 0; jk < 4; ++jk) {
      float p[8];
#pragma unroll
      for (int c = 0; c < 8; ++c) {
        float sv = (jk < 2) ? sfr0[(jk & 1) * 8 + c] : sfr1[(jk & 1) * 8 + c];
        p[c] = __builtin_amdgcn_exp2f(sv * K1);
      }
      psum += ((p[0] + p[1]) + (p[2] + p[3])) + ((p[4] + p[5]) + (p[6] + p[7]));
      unsigned X0 = cvtpk_bf16(p[0], p[1]);
      unsigned X1 = cvtpk_bf16(p[2], p[3]);
      unsigned Y0 = cvtpk_bf16(p[4], p[5]);
      unsigned Y1 = cvtpk_bf16(p[6], p[7]);
      pl32swap(X0, Y0);
      pl32swap(X1, Y1);
      union { unsigned u[4]; bf16x8 v; } pu;
      pu.u[0] = X0; pu.u[1] = X1; pu.u[2] = Y0; pu.u[3] = Y1;
      pfr[jk] = pu.v;
    }
    l_run += psum;

#pragma unroll
    for (int jk = 0; jk < 4; ++jk) {
      int sw = ((jk * 32 + hi * 16) ^ ((col & 7) << 4));
      bf16x8 vf0 = *(const bf16x8*)(Vc + col * 128 + sw);
      bf16x8 vf1 = *(const bf16x8*)(Vc + (32 + col) * 128 + sw);
      oacc0 = mfma32(vf0, pfr[jk], oacc0);
      oacc1 = mfma32(vf1, pfr[jk], oacc1);
    }

    WAITVM0;
    __builtin_amdgcn_s_barrier();
    __builtin_amdgcn_sched_barrier(0);
    cur ^= 1;
  }
#undef STAGE

  l_run += __shfl_xor(l_run, 32);
  float linv = 1.0f / l_run;
  if (hi == 0)
    lbuf[(((size_t)bh * 16 + blockIdx.x) * 2 + jh) * 128 + w * 32 + col] = l_run;

  char* Ow = Klds + w * 4096;  // [32 i][128B d-row], swizzled
#pragma unroll
  for (int da = 0; da < 2; ++da) {
    const f32x16& oa = da ? oacc1 : oacc0;
#pragma unroll
    for (int g = 0; g < 4; ++g) {
      unsigned w0 = cvtpk_bf16(oa[g * 4 + 0] * linv, oa[g * 4 + 1] * linv);
      unsigned w1 = cvtpk_bf16(oa[g * 4 + 2] * linv, oa[g * 4 + 3] * linv);
      int dby = da * 64 + g * 16 + hi * 8;
      char* dst = Ow + col * 128 + ((dby & ~15) ^ ((col & 7) << 4)) + (dby & 8);
      u32x2 pr = {w0, w1};
      *(u32x2*)dst = pr;
    }
  }
  int rr0 = ln >> 3, c16o = ln & 7;
#pragma unroll
  for (int pp = 0; pp < 4; ++pp) {
    int rr = rr0 + pp * 8;
    bf16x8 ov = *(const bf16x8*)(Ow + rr * 128 + ((c16o * 16) ^ ((rr & 7) << 4)));
    int grow = bq * 2048 + q0 + w * 32 + rr;
    *(bf16x8*)(Oh + (size_t)grow * 1024 + h * 64 + c16o * 8) = ov;
  }
}

// ------------------------------------------------------------- combine
// vectorized — 8 elems (16B)/thread, grid 2048x256 (r12-verified).
__global__ __launch_bounds__(256) void combine_kernel(
    __bf16* __restrict__ O0, const __bf16* __restrict__ O1,
    const float* __restrict__ lbuf) {
  int idx = blockIdx.x * 256 + threadIdx.x;
  int e0 = idx * 8;
  int r = e0 >> 10, c0 = e0 & 1023;
  int b = r >> 11, seq = r & 2047, qb = seq >> 7, i = seq & 127;
  int h = c0 >> 6;
  int bh = b * 16 + h;
  size_t lbase = (((size_t)bh * 16 + qb) * 2) * 128 + i;
  float l0 = lbuf[lbase], l1 = lbuf[lbase + 128];
  float inv = 1.0f / (l0 + l1);
  float w0 = l0 * inv, w1 = l1 * inv;
  bf16x8 a = *(const bf16x8*)(O0 + e0);
  bf16x8 bb = *(const bf16x8*)(O1 + e0);
  unsigned u[4];
#pragma unroll
  for (int j = 0; j < 4; ++j) {
    float lo = w0 * bf16_f32(a[2 * j]) + w1 * bf16_f32(bb[2 * j]);
    float hi2 = w0 * bf16_f32(a[2 * j + 1]) + w1 * bf16_f32(bb[2 * j + 1]);
    u[j] = cvtpk_bf16(lo, hi2);
  }
  union { unsigned uu[4]; bf16x8 v; } pu;
  pu.uu[0] = u[0]; pu.uu[1] = u[1]; pu.uu[2] = u[2]; pu.uu[3] = u[3];
  *(bf16x8*)(O0 + e0) = pu.v;
}

// ---------------------------------------------------------------- launch
extern "C" void kernel_launch(void* const* d_in, const int* in_sizes, int n_in,
                              void* d_out, int out_size, void* d_ws, size_t ws_size,
                              hipStream_t stream) {
  const float* x = (const float*)d_in[0];
  const float* gamma = (const float*)d_in[1];
  const float* beta = (const float*)d_in[2];
  const float* w_qkv = (const float*)d_in[3];
  const float* w_out = (const float*)d_in[4];
  const float* b_out = (const float*)d_in[5];

  char* ws = (char*)d_ws;
  // [0..8): xn / attn half-0 partial / final sa (in-place combine)
  // [8..16): attn half-1 partial
  // [16..22): wqkvT (dead after QKV GEMM; first 1MB reused as lbuf by attn)
  // [22..24): woutT
  // [24..32): Qb   [32..40): Kb   [40..48): VTb
  __bf16* xn = (__bf16*)(ws);
  __bf16* Opart = xn;                               // halves at +0MB / +8MB
  float* lbuf = (float*)(ws + (16l << 20));
  __bf16* wqkvT = (__bf16*)(ws + (16l << 20));
  __bf16* woutT = (__bf16*)(ws + (22l << 20));
  __bf16* Qb = (__bf16*)(ws + (24l << 20));
  __bf16* Kb = (__bf16*)(ws + (32l << 20));
  __bf16* VTb = (__bf16*)(ws + (40l << 20));
  __bf16* sa = xn;  // combine merges half-1 into half-0 in place

  prep_kernel<<<5120, 256, 0, stream>>>(x, gamma, beta, xn, w_qkv, wqkvT,
                                        w_out, woutT);
  gemm_qkv_kernel<<<dim3(24, 32), 256, 0, stream>>>(xn, wqkvT, Qb, Kb, VTb);
  attn_kernel<<<dim3(16, 32, 2), 256, 0, stream>>>(Qb, Kb, VTb, Opart, lbuf);
  combine_kernel<<<2048, 256, 0, stream>>>(sa, Opart + (4096l * 1024), lbuf);
  gemm_out_kernel<<<dim3(16, 32), 256, 0, stream>>>(sa, woutT, (float*)d_out, b_out);
}